// Round 1
// baseline (509.133 us; speedup 1.0000x reference)
//
#include <hip/hip_runtime.h>

// ---------------------------------------------------------------------------
// SpatialTransformerPyramid2d: fused Laplacian-pyramid + bilinear sample +
// feature contraction for N=64, c=32, H=W=128, outdims=4096, SCALE_N=4.
//
// Key identity: bilinear(hi_k) = bilinear(img_k) - 4 * (3x3 stencil on lo_{k+1})
// since the two corners of the bilinear combine the even/odd transposed-conv
// taps into at most 3 taps per axis.
//
// Block = (n, channel-pair). LDS holds lo1(64^2)+lo2(32^2)+lo3(16^2)+lo4(8^2)
// = 5440 floats per channel -> 43520 B per block -> 3 blocks/CU.
// ---------------------------------------------------------------------------

#define SLOT 5440          // floats per channel slot in LDS
#define OFF_LO1 0
#define OFF_LO2 4096
#define OFF_LO3 5120
#define OFF_LO4 5376

static __device__ __forceinline__ float clampf(float v, float lo, float hi) {
    return fminf(fmaxf(v, lo), hi);
}
static __device__ __forceinline__ int imin(int a, int b) { return a < b ? a : b; }
static __device__ __forceinline__ int imax(int a, int b) { return a > b ? a : b; }

// separable 1D Gaussian factor of the reference 5x5 _G (outer product matches
// _G to ~2e-7, far below the 1.3e-2 absmax threshold)
#define G_A 0.0613609f
#define G_B 0.2447700f
#define G_C 0.3877386f

__global__ void init_out_kernel(const float* __restrict__ bias, float* __restrict__ y) {
    int i = blockIdx.x * blockDim.x + threadIdx.x;
    y[i] = bias[i & 4095];
}

// smooth-and-downsample one output point: lo[i,j] = sum G[dy,dx]*src[2i+dy-2, 2j+dx-2]
// (zero padding outside [0,S) x [0,S)). ld(idx) returns src[idx] for idx = row*S+col.
template <typename LD>
static __device__ __forceinline__ float down_pt(LD ld, int S, int i, int j) {
    const float g1[5] = {G_A, G_B, G_C, G_B, G_A};
    int by = 2 * i - 2, bx = 2 * j - 2;
    float acc = 0.f;
    int hi = (S >> 1) - 2;
    if (i >= 1 && i <= hi && j >= 1 && j <= hi) {
#pragma unroll
        for (int dy = 0; dy < 5; ++dy) {
            int rb = (by + dy) * S + bx;
            float r = g1[0] * ld(rb) + g1[1] * ld(rb + 1) + g1[2] * ld(rb + 2) +
                      g1[3] * ld(rb + 3) + g1[4] * ld(rb + 4);
            acc += g1[dy] * r;
        }
    } else {
#pragma unroll
        for (int dy = 0; dy < 5; ++dy) {
            int yy = by + dy;
            if ((unsigned)yy < (unsigned)S) {
#pragma unroll
                for (int dx = 0; dx < 5; ++dx) {
                    int xx = bx + dx;
                    if ((unsigned)xx < (unsigned)S) acc += g1[dy] * g1[dx] * ld(yy * S + xx);
                }
            }
        }
    }
    return acc;
}

__global__ __launch_bounds__(256, 3) void pyr_sample_kernel(
    const float* __restrict__ x, const float* __restrict__ grid,
    const float* __restrict__ feat, float* __restrict__ y)
{
    __shared__ float s_lo[2 * SLOT];
    const int tid = threadIdx.x;
    const int n   = blockIdx.x >> 4;        // 64 n
    const int c0  = (blockIdx.x & 15) << 1; // 16 channel-pairs

    const float* img0 = x + ((size_t)(n * 32 + c0) << 14); // 128*128 = 16384

    // ---- phase 1: lo1 (64x64) for both channels, reading x from global ----
    for (int pos = tid; pos < 2 * 4096; pos += 256) {
        int gi = pos >> 12, p = pos & 4095;
        int i = p >> 6, j = p & 63;
        const float* img = img0 + ((size_t)gi << 14);
        s_lo[gi * SLOT + OFF_LO1 + p] = down_pt([&](int idx) { return img[idx]; }, 128, i, j);
    }
    __syncthreads();

    // ---- phase 2: lo2 (32x32) ----
    for (int pos = tid; pos < 2 * 1024; pos += 256) {
        int gi = pos >> 10, p = pos & 1023;
        int i = p >> 5, j = p & 31;
        int base = gi * SLOT;
        s_lo[base + OFF_LO2 + p] =
            down_pt([&](int idx) { return s_lo[base + OFF_LO1 + idx]; }, 64, i, j);
    }
    __syncthreads();

    // ---- phase 3: lo3 (16x16) ----
    for (int pos = tid; pos < 2 * 256; pos += 256) {
        int gi = pos >> 8, p = pos & 255;
        int i = p >> 4, j = p & 15;
        int base = gi * SLOT;
        s_lo[base + OFF_LO3 + p] =
            down_pt([&](int idx) { return s_lo[base + OFF_LO2 + idx]; }, 32, i, j);
    }
    __syncthreads();

    // ---- phase 4: lo4 (8x8) ----
    if (tid < 2 * 64) {
        int gi = tid >> 6, p = tid & 63;
        int i = p >> 3, j = p & 7;
        int base = gi * SLOT;
        s_lo[base + OFF_LO4 + p] =
            down_pt([&](int idx) { return s_lo[base + OFF_LO2 + OFF_LO3 - OFF_LO2 + idx]; }, 16, i, j);
    }
    __syncthreads();

    // ---- phase 5: sample all 4096 points, contract with feat, atomicAdd ----
    for (int out = tid; out < 4096; out += 256) {
        float xs = clampf(grid[2 * out + 0], -1.f, 1.f);
        float ys = clampf(grid[2 * out + 1], -1.f, 1.f);
        float acc0 = 0.f, acc1 = 0.f;
#pragma unroll
        for (int k = 0; k < 5; ++k) {
            const int Wk = 128 >> k;            // level image dim
            const int Wl = 64 >> k;             // lo (next level) dim, k<4
            const int img_off = (k == 1) ? OFF_LO1 : (k == 2) ? OFF_LO2
                              : (k == 3) ? OFF_LO3 : OFF_LO4;  // k==0 unused
            const int lo_off  = (k == 0) ? OFF_LO1 : (k == 1) ? OFF_LO2
                              : (k == 2) ? OFF_LO3 : OFF_LO4;  // k==4 unused

            float fx = ((xs + 1.f) * (float)Wk - 1.f) * 0.5f;
            float fy = ((ys + 1.f) * (float)Wk - 1.f) * 0.5f;
            float x0f = floorf(fx), y0f = floorf(fy);
            int x0 = (int)x0f, y0 = (int)y0f;
            float wx = fx - x0f, wy = fy - y0f;
            // corner weights with validity folded in (validity is separable)
            float ux0 = (x0 >= 0)     ? (1.f - wx) : 0.f;
            float ux1 = (x0 + 1 < Wk) ? wx         : 0.f;
            float uy0 = (y0 >= 0)     ? (1.f - wy) : 0.f;
            float uy1 = (y0 + 1 < Wk) ? wy         : 0.f;
            int cx0 = imax(x0, 0), cx1 = imin(x0 + 1, Wk - 1);
            int cy0 = imax(y0, 0), cy1 = imin(y0 + 1, Wk - 1);
            float w00 = ux0 * uy0, w01 = ux1 * uy0, w10 = ux0 * uy1, w11 = ux1 * uy1;

            float twx[3], twy[3];
            int txi[3], tyi[3];
            if (k < 4) {
                // combined 3-tap 1D stencils of bilinear(upsample(lo))
                int qx;
                if (x0 & 1) {   // x0 odd -> taps {q, q+1, q+2}, q=(x0-1)/2
                    qx = (x0 - 1) >> 1;
                    twx[0] = G_B * ux0 + G_A * ux1;
                    twx[1] = G_B * ux0 + G_C * ux1;
                    twx[2] = G_A * ux1;
                } else {        // x0 even -> taps {q-1, q, q+1}, q=x0/2
                    qx = (x0 >> 1) - 1;
                    twx[0] = G_A * ux0;
                    twx[1] = G_C * ux0 + G_B * ux1;
                    twx[2] = G_A * ux0 + G_B * ux1;
                }
                int qy;
                if (y0 & 1) {
                    qy = (y0 - 1) >> 1;
                    twy[0] = G_B * uy0 + G_A * uy1;
                    twy[1] = G_B * uy0 + G_C * uy1;
                    twy[2] = G_A * uy1;
                } else {
                    qy = (y0 >> 1) - 1;
                    twy[0] = G_A * uy0;
                    twy[1] = G_C * uy0 + G_B * uy1;
                    twy[2] = G_A * uy0 + G_B * uy1;
                }
#pragma unroll
                for (int t = 0; t < 3; ++t) {
                    int ix = qx + t;
                    if (ix < 0 || ix >= Wl) twx[t] = 0.f;
                    txi[t] = imin(imax(ix, 0), Wl - 1);
                    int iy = qy + t;
                    if (iy < 0 || iy >= Wl) twy[t] = 0.f;
                    tyi[t] = imin(imax(iy, 0), Wl - 1);
                }
            }

#pragma unroll
            for (int gi = 0; gi < 2; ++gi) {
                const int sbase = gi * SLOT;
                float i00, i01, i10, i11;
                if (k == 0) {
                    const float* im = img0 + ((size_t)gi << 14);
                    i00 = im[cy0 * 128 + cx0]; i01 = im[cy0 * 128 + cx1];
                    i10 = im[cy1 * 128 + cx0]; i11 = im[cy1 * 128 + cx1];
                } else {
                    const int ib = sbase + img_off;
                    i00 = s_lo[ib + cy0 * Wk + cx0]; i01 = s_lo[ib + cy0 * Wk + cx1];
                    i10 = s_lo[ib + cy1 * Wk + cx0]; i11 = s_lo[ib + cy1 * Wk + cx1];
                }
                float val = w00 * i00 + w01 * i01 + w10 * i10 + w11 * i11;
                if (k < 4) {
                    const int lb = sbase + lo_off;
                    float upv = 0.f;
#pragma unroll
                    for (int iy = 0; iy < 3; ++iy) {
                        int rb = lb + tyi[iy] * Wl;
                        float r = twx[0] * s_lo[rb + txi[0]] +
                                  twx[1] * s_lo[rb + txi[1]] +
                                  twx[2] * s_lo[rb + txi[2]];
                        upv += twy[iy] * r;
                    }
                    val -= 4.f * upv;
                }
                float f = feat[((size_t)(k * 32 + c0 + gi) << 12) + out];
                if (gi == 0) acc0 += f * val; else acc1 += f * val;
            }
        }
        atomicAdd(&y[(n << 12) + out], acc0 + acc1);
    }
}

extern "C" void kernel_launch(void* const* d_in, const int* in_sizes, int n_in,
                              void* d_out, int out_size, void* d_ws, size_t ws_size,
                              hipStream_t stream) {
    (void)in_sizes; (void)n_in; (void)d_ws; (void)ws_size;
    const float* x    = (const float*)d_in[0];
    const float* grid = (const float*)d_in[1];
    const float* feat = (const float*)d_in[2];
    const float* bias = (const float*)d_in[3];
    float* y = (float*)d_out;

    init_out_kernel<<<out_size / 256, 256, 0, stream>>>(bias, y);
    pyr_sample_kernel<<<1024, 256, 0, stream>>>(x, grid, feat, y);
}